// Round 1
// 62.490 us; speedup vs baseline: 1.0526x; 1.0526x over previous
//
#include <hip/hip_runtime.h>

#define RCR 5.2f
#define RCA 3.5f
#define PI_F 3.14159265358979323846f

// 1024 blocks (one per central atom (c,i)), 256 threads = 4 waves.
//   Phase 0: every wave redundantly computes per-neighbor data (lane = neighbor);
//            wave 0 writes the float4-packed compacted LDS tables; all four waves
//            cooperatively build the pair list (b strided by wave).
//   Radial:  lane owns slot (species s = l>>4, shell r = l&15); the m-loop is
//            split across the 4 waves; partial sums reduced via ds_add_f32.
//   Angular: 8 pairs in flight per block-iteration (2 per wave, 32 lanes per
//            pair, one (shell,angle) slot per lane); next pairab entry is
//            prefetched one iteration ahead to hide LDS latency.
__global__ __launch_bounds__(256)
void aev_kernel(const int* __restrict__ species,
                const float* __restrict__ coords,
                float* __restrict__ out)
{
    const int blk = blockIdx.x;     // c*64 + i
    const int c   = blk >> 6;
    const int i   = blk & 63;
    const int tid = threadIdx.x;
    const int l   = tid & 63;       // lane == neighbor index
    const int w   = tid >> 6;       // wave id 0..3

    // ---- per-neighbor data in registers (all waves, identical) ----
    const int gbase = (c * 64 + l) * 3;
    float x = coords[gbase + 0];
    float y = coords[gbase + 1];
    float z = coords[gbase + 2];
    int  sp = species[c * 64 + l];

    float xi = __shfl(x, i);
    float yi = __shfl(y, i);
    float zi = __shfl(z, i);

    float rx = xi - x, ry = yi - y, rz = zi - z;
    float d  = sqrtf(rx * rx + ry * ry + rz * rz);
    bool valid  = (l != i) && (sp != -1);
    bool rvalid = valid && (d <= RCR);
    bool avalid = valid && (d <= RCA);

    __shared__ float4 ang0[64];     // rx, ry, rz, d
    __shared__ float4 ang1[64];     // 1/d, fc_a, species(bits), 0
    __shared__ float4 radf[64];     // d, fc_r, species(bits), 0
    __shared__ int    pairab[1953]; // worst case 63*62/2
    __shared__ float  acc[320];
    __shared__ float  raccs[64];

    for (int t = tid; t < 320; t += 256) acc[t] = 0.f;
    if (tid < 64) raccs[tid] = 0.f;

    unsigned long long rmask = __ballot(rvalid);
    unsigned long long amask = __ballot(avalid);
    const int nr = __popcll(rmask);
    const int n  = __popcll(amask);

    if (w == 0) {
        const unsigned long long below = (l == 0) ? 0ull : (~0ull >> (64 - l));
        if (rvalid) {
            int pos = __popcll(rmask & below);
            radf[pos] = make_float4(d,
                                    0.5f * __cosf(PI_F * d * (1.0f / RCR)) + 0.5f,
                                    __int_as_float(sp), 0.f);
        }
        if (avalid) {
            int pos = __popcll(amask & below);
            ang0[pos] = make_float4(rx, ry, rz, d);
            ang1[pos] = make_float4(1.0f / fmaxf(d, 1e-8f),
                                    0.5f * __cosf(PI_F * d * (1.0f / RCA)) + 0.5f,
                                    __int_as_float(sp), 0.f);
        }
    }
    // pair list over compacted angular indices; rows = lanes, b strided by wave
    if (l < n) {
        const int base = l * (n - 1) - (l * (l - 1)) / 2;
        for (int b = l + 1 + w; b < n; b += 4)
            pairab[base + (b - l - 1)] = (l << 6) | b;
    }
    __syncthreads();

    // ---- radial: lane l owns slot (s = l>>4, shell = l&15); m split by wave ----
    const int   s   = l >> 4;
    const float shf = 0.9f + 0.26875f * (float)(l & 15);
    float racc = 0.f;
    for (int m = w; m < nr; m += 4) {
        float4 rv  = radf[m];
        float  dd  = rv.x - shf;
        float  term = 0.25f * __expf(-16.f * dd * dd) * rv.y;
        racc += (__float_as_int(rv.z) == s) ? term : 0.f;
    }
    atomicAdd(&raccs[l], racc);

    // ---- angular: 2 pairs per wave per iteration, 8 pairs per block-iter ----
    const int   sub  = l & 31;                         // aa*8 + z
    const float shfa = 0.9f + 0.65f * (float)(sub >> 3);
    const float shfz = PI_F / 16.f + (PI_F / 8.f) * (float)(sub & 7);
    const float czv  = __cosf(shfz);
    const float szv  = __sinf(shfz);
    const int   np   = (n * (n - 1)) >> 1;
    const int   half = l >> 5;

    int p0_first = w * 2;
    int p_pf = p0_first + half;
    int ab   = (p_pf < np) ? pairab[p_pf] : 0;         // prefetched entry
    for (int p0 = p0_first; p0 < np; p0 += 8) {
        const int pc   = p0 + half;
        const int ab_c = ab;
        const int pn   = p0 + 8 + half;
        if (pn < np) ab = pairab[pn];                  // prefetch next iter
        if (pc < np) {
            const int a = ab_c >> 6, b = ab_c & 63;
            float4 A0 = ang0[a], A1 = ang1[a];
            float4 B0 = ang0[b], B1 = ang1[b];
            float dot = A0.x * B0.x + A0.y * B0.y + A0.z * B0.z;
            float ca  = 0.95f * dot * A1.x * B1.x;
            float sa  = sqrtf(fmaxf(0.f, 1.f - ca * ca));
            float dm  = 0.5f * (A0.w + B0.w);
            float fprod = 2.f * A1.y * B1.y;
            int s1 = __float_as_int(A1.z), s2 = __float_as_int(B1.z);
            int mn = min(s1, s2), mx = max(s1, s2);
            int pid = ((mn * (7 - mn)) >> 1) + mx;
            float cdz = ca * czv + sa * szv;
            float t = 0.5f + 0.5f * cdz;
            t = t * t; t = t * t; t = t * t; t = t * t; t = t * t;  // ^32
            float u = dm - shfa;
            float val = t * __expf(-8.f * u * u) * fprod;
            atomicAdd(&acc[pid * 32 + sub], val);
        }
    }
    __syncthreads();

    // ---- epilogue: 384 floats, coalesced ----
    const long ob = (long)blk * 384;
    if (tid < 64) out[ob + tid] = raccs[tid];
    for (int t = tid; t < 320; t += 256) out[ob + 64 + t] = acc[t];
}

extern "C" void kernel_launch(void* const* d_in, const int* in_sizes, int n_in,
                              void* d_out, int out_size, void* d_ws, size_t ws_size,
                              hipStream_t stream) {
    const int* species  = (const int*)d_in[0];
    const float* coords = (const float*)d_in[1];
    float* out          = (float*)d_out;
    aev_kernel<<<dim3(16 * 64), dim3(256), 0, stream>>>(species, coords, out);
}

// Round 2
// 60.569 us; speedup vs baseline: 1.0860x; 1.0317x over previous
//
#include <hip/hip_runtime.h>

#define RCR 5.2f
#define RCA 3.5f
#define PI_F 3.14159265358979323846f

// 1024 blocks (one per central atom (c,i)), 256 threads = 4 waves.
//   Phase 0: all waves compute per-neighbor data (lane = neighbor); wave 0
//            writes float4-packed compacted LDS tables. No pair list —
//            pairs are decoded analytically from the flat index.
//   Radial:  lane owns slot (species s = l>>4, shell r = l&15); the m-loop is
//            split across the 4 waves; partials in raccs4, summed in epilogue.
//   Angular: 16 pairs in flight per block-iteration (2 per half-wave, ILP
//            unrolled; 32 lanes per pair, one (shell,angle) slot per lane).
__global__ __launch_bounds__(256)
void aev_kernel(const int* __restrict__ species,
                const float* __restrict__ coords,
                float* __restrict__ out)
{
    const int blk = blockIdx.x;     // c*64 + i
    const int c   = blk >> 6;
    const int i   = blk & 63;
    const int tid = threadIdx.x;
    const int l   = tid & 63;       // lane == neighbor index
    const int w   = tid >> 6;       // wave id 0..3

    // ---- per-neighbor data in registers (all waves, identical) ----
    const int gbase = (c * 64 + l) * 3;
    float x = coords[gbase + 0];
    float y = coords[gbase + 1];
    float z = coords[gbase + 2];
    int  sp = species[c * 64 + l];

    float xi = __shfl(x, i);
    float yi = __shfl(y, i);
    float zi = __shfl(z, i);

    float rx = xi - x, ry = yi - y, rz = zi - z;
    float d  = sqrtf(rx * rx + ry * ry + rz * rz);
    bool valid  = (l != i) && (sp != -1);
    bool rvalid = valid && (d <= RCR);
    bool avalid = valid && (d <= RCA);

    __shared__ float4 ang0[64];     // rx, ry, rz, d
    __shared__ float4 ang1[64];     // 1/d, fc_a, species(bits), 0
    __shared__ float4 radf[64];     // d, fc_r, species(bits), 0
    __shared__ float  acc[320];
    __shared__ float  raccs4[4][64];

    for (int t = tid; t < 320; t += 256) acc[t] = 0.f;

    unsigned long long rmask = __ballot(rvalid);
    unsigned long long amask = __ballot(avalid);
    const int nr = __popcll(rmask);
    const int n  = __popcll(amask);

    if (w == 0) {
        const unsigned long long below = (l == 0) ? 0ull : (~0ull >> (64 - l));
        if (rvalid) {
            int pos = __popcll(rmask & below);
            radf[pos] = make_float4(d,
                                    0.5f * __cosf(PI_F * d * (1.0f / RCR)) + 0.5f,
                                    __int_as_float(sp), 0.f);
        }
        if (avalid) {
            int pos = __popcll(amask & below);
            ang0[pos] = make_float4(rx, ry, rz, d);
            ang1[pos] = make_float4(1.0f / fmaxf(d, 1e-8f),
                                    0.5f * __cosf(PI_F * d * (1.0f / RCA)) + 0.5f,
                                    __int_as_float(sp), 0.f);
        }
    }
    __syncthreads();

    // ---- radial: lane l owns slot (s = l>>4, shell = l&15); m split by wave ----
    const int   s   = l >> 4;
    const float shf = 0.9f + 0.26875f * (float)(l & 15);
    float racc = 0.f;
    for (int m = w; m < nr; m += 4) {
        float4 rv  = radf[m];
        float  dd  = rv.x - shf;
        float  term = 0.25f * __expf(-16.f * dd * dd) * rv.y;
        racc += (__float_as_int(rv.z) == s) ? term : 0.f;
    }
    raccs4[w][l] = racc;

    // ---- angular: analytic pair decode; 2 pairs per half-wave per iter ----
    const int   sub  = l & 31;                         // aa*8 + z
    const float shfa = 0.9f + 0.65f * (float)(sub >> 3);
    const float shfz = PI_F / 16.f + (PI_F / 8.f) * (float)(sub & 7);
    const float czv  = __cosf(shfz);
    const float szv  = __sinf(shfz);
    const int   np   = (n * (n - 1)) >> 1;
    const int   lane_pair = (w << 1) + (l >> 5);       // 0..7

    auto do_pair = [&](int p) {
        if (p < np) {
            // invert triangular index (rows a ascending with n-1-a entries)
            int rev = np - 1 - p;
            int k = (int)floorf((sqrtf((float)(8 * rev + 1)) - 1.0f) * 0.5f);
            int tk = (k * (k + 1)) >> 1;
            if (tk > rev)                          { --k; tk = (k * (k + 1)) >> 1; }
            else if (((k + 1) * (k + 2)) >> 1 <= rev) { ++k; tk = (k * (k + 1)) >> 1; }
            const int a = n - 2 - k;
            const int b = n - 1 - (rev - tk);

            float4 A0 = ang0[a], A1 = ang1[a];
            float4 B0 = ang0[b], B1 = ang1[b];
            float dot = A0.x * B0.x + A0.y * B0.y + A0.z * B0.z;
            float ca  = 0.95f * dot * A1.x * B1.x;
            float sa  = sqrtf(fmaxf(0.f, 1.f - ca * ca));
            float dm  = 0.5f * (A0.w + B0.w);
            float fprod = 2.f * A1.y * B1.y;
            int s1 = __float_as_int(A1.z), s2 = __float_as_int(B1.z);
            int mn = min(s1, s2), mx = max(s1, s2);
            int pid = ((mn * (7 - mn)) >> 1) + mx;
            float cdz = ca * czv + sa * szv;
            float t = 0.5f + 0.5f * cdz;
            t = t * t; t = t * t; t = t * t; t = t * t; t = t * t;  // ^32
            float u = dm - shfa;
            float val = t * __expf(-8.f * u * u) * fprod;
            atomicAdd(&acc[pid * 32 + sub], val);
        }
    };

    for (int p0 = 0; p0 < np; p0 += 16) {
        do_pair(p0 + lane_pair);          // two independent pair bodies
        do_pair(p0 + 8 + lane_pair);      // interleave for ILP / latency hiding
    }
    __syncthreads();

    // ---- epilogue: 384 floats, coalesced ----
    const long ob = (long)blk * 384;
    if (tid < 64)
        out[ob + tid] = raccs4[0][tid] + raccs4[1][tid]
                      + raccs4[2][tid] + raccs4[3][tid];
    for (int t = tid; t < 320; t += 256) out[ob + 64 + t] = acc[t];
}

extern "C" void kernel_launch(void* const* d_in, const int* in_sizes, int n_in,
                              void* d_out, int out_size, void* d_ws, size_t ws_size,
                              hipStream_t stream) {
    const int* species  = (const int*)d_in[0];
    const float* coords = (const float*)d_in[1];
    float* out          = (float*)d_out;
    aev_kernel<<<dim3(16 * 64), dim3(256), 0, stream>>>(species, coords, out);
}